// Round 3
// baseline (660.095 us; speedup 1.0000x reference)
//
#include <hip/hip_runtime.h>
#include <hip/hip_bf16.h>
#include <math.h>

// Problem constants
#define BB 8
#define SS 2048
#define TT (BB * SS)      // 16384 tokens
#define DM 256
#define DI 512
#define DSTATE 16
#define DCONV 4
#define NLAYERS 2
#define VOCAB 256
#define LOG_VOCAB 5.545177444479562f
#define RMS_EPS 1.1920929e-07f
#define LOG2E 1.4426950408889634f
#define LN2 0.6931471805599453f

typedef __attribute__((ext_vector_type(8))) __bf16 bf16x8;
typedef __attribute__((ext_vector_type(2))) __bf16 bf16x2;
typedef __attribute__((ext_vector_type(4))) float f32x4;

// ---- fast transcendentals: raw v_exp/v_log/v_rcp (1-ulp class; entropy
// margin vs THR=0.5 is ~0.4, so this precision cannot flip a boundary) ----
__device__ __forceinline__ float fexp(float x) {   // e^x
  return __builtin_amdgcn_exp2f(x * LOG2E);
}
__device__ __forceinline__ float fexp2(float x) {  // 2^x
  return __builtin_amdgcn_exp2f(x);
}
__device__ __forceinline__ float flog(float x) {   // ln x
  return __builtin_amdgcn_logf(x) * LN2;
}
__device__ __forceinline__ float frcp(float x) {
  return __builtin_amdgcn_rcpf(x);
}
__device__ __forceinline__ float fsigmoid(float x) {
  return frcp(1.f + fexp(-x));
}
__device__ __forceinline__ float fsoftplus(float x) {
  return fmaxf(x, 0.f) + flog(1.f + fexp(-fabsf(x)));
}

// ---------------------------------------------------------------------------
// bf16 MFMA GEMM (m97 structure): C[M,N] = A[M,K] @ Bt[N,K]^T
// 128x128 block tile, BK=32, 256 threads (4 waves, each 64x64),
// global_load_lds width-16 staging, 16x16x32 bf16 MFMA.
// ---------------------------------------------------------------------------
__device__ __forceinline__ void gl2lds16(const void* g, void* l) {
  __builtin_amdgcn_global_load_lds(
      (const __attribute__((address_space(1))) void*)g,
      (__attribute__((address_space(3))) void*)l, 16, 0, 0);
}

template <typename T> __device__ __forceinline__ T cvt_out(float v);
template <> __device__ __forceinline__ float cvt_out<float>(float v) { return v; }
template <> __device__ __forceinline__ __hip_bfloat16 cvt_out<__hip_bfloat16>(float v) {
  return __float2bfloat16(v);
}

template <typename OutT>
__global__ __launch_bounds__(256) void gemm_mfma(
    const __bf16* __restrict__ A,   // [M][K]
    const __bf16* __restrict__ Bt,  // [N][K]  (W^T)
    OutT* __restrict__ C,           // [M][N]
    int M, int N, int K) {
  __shared__ __align__(16) __bf16 As[128 * 32];
  __shared__ __align__(16) __bf16 Bs[128 * 32];
  int tid = threadIdx.x;
  int lane = tid & 63;
  int wave = tid >> 6;
  int wm = (wave & 1) * 64;
  int wn = (wave >> 1) * 64;
  int m0 = blockIdx.y * 128;
  int n0 = blockIdx.x * 128;

  int r = tid >> 2;
  int kc = (tid & 3) * 8;
  int fr = lane & 15;
  int fk = (lane >> 4) * 8;

  f32x4 acc[4][4] = {};

  for (int k0 = 0; k0 < K; k0 += 32) {
    gl2lds16(A + (size_t)(m0 + r) * K + k0 + kc, As + r * 32 + kc);
    gl2lds16(A + (size_t)(m0 + 64 + r) * K + k0 + kc, As + (64 + r) * 32 + kc);
    gl2lds16(Bt + (size_t)(n0 + r) * K + k0 + kc, Bs + r * 32 + kc);
    gl2lds16(Bt + (size_t)(n0 + 64 + r) * K + k0 + kc, Bs + (64 + r) * 32 + kc);
    __syncthreads();

    bf16x8 af[4], bfr[4];
#pragma unroll
    for (int i = 0; i < 4; ++i) {
      af[i] = *(const bf16x8*)(As + (wm + i * 16 + fr) * 32 + fk);
      bfr[i] = *(const bf16x8*)(Bs + (wn + i * 16 + fr) * 32 + fk);
    }
#pragma unroll
    for (int i = 0; i < 4; ++i)
#pragma unroll
      for (int j = 0; j < 4; ++j)
        acc[i][j] = __builtin_amdgcn_mfma_f32_16x16x32_bf16(af[i], bfr[j], acc[i][j], 0, 0, 0);
    __syncthreads();
  }

  int cr = (lane >> 4) * 4;
  int cc = lane & 15;
#pragma unroll
  for (int i = 0; i < 4; ++i) {
    int mrow = m0 + wm + i * 16 + cr;
#pragma unroll
    for (int j = 0; j < 4; ++j) {
      int ncol = n0 + wn + j * 16 + cc;
#pragma unroll
      for (int rg = 0; rg < 4; ++rg)
        C[(size_t)(mrow + rg) * N + ncol] = cvt_out<OutT>(acc[i][j][rg]);
    }
  }
}

// ---------------------------------------------------------------------------
// Weight prep: transpose + cast fp32 [K][N] -> bf16 [N][K]
// ---------------------------------------------------------------------------
__global__ void tcast_kernel(const float* __restrict__ src, __hip_bfloat16* __restrict__ dst,
                             int K, int N) {
  int i = blockIdx.x * 256 + threadIdx.x;
  if (i >= K * N) return;
  int n = i / K, k = i - n * K;
  dst[i] = __float2bfloat16(src[(size_t)k * N + n]);
}

// A2 = -exp(A_log) * log2(e)   (exp2-ready SSM decay coefficients)
__global__ void aneg_kernel(const float* __restrict__ a_log, float* __restrict__ a2, int n) {
  int i = blockIdx.x * blockDim.x + threadIdx.x;
  if (i < n) a2[i] = -fexp(a_log[i]) * LOG2E;
}

// embedding gather -> x fp32 + xb bf16
__global__ void embed_kernel(const int* __restrict__ bytes, const float* __restrict__ ew,
                             float* __restrict__ x, __hip_bfloat16* __restrict__ xb) {
  int t = blockIdx.x;
  int c = threadIdx.x;
  float v = ew[(size_t)bytes[t] * DM + c];
  x[(size_t)t * DM + c] = v;
  xb[(size_t)t * DM + c] = __float2bfloat16(v);
}

// causal depthwise conv (width 4, left pad 3) + bias + silu.
// xin = xz[:, 0:512] (row stride 1024, bf16). Writes xc bf16.
__global__ void conv_silu_kernel(const __hip_bfloat16* __restrict__ xz,
                                 const float* __restrict__ cw, const float* __restrict__ cb,
                                 __hip_bfloat16* __restrict__ xc) {
  int t = blockIdx.x;
  int s = t & (SS - 1);
  int d0 = threadIdx.x * 2;
  const bf16x2* src = (const bf16x2*)(xz + (size_t)t * (2 * DI) + d0);
  float acc0 = cb[d0], acc1 = cb[d0 + 1];
#pragma unroll
  for (int k = 0; k < DCONV; ++k) {
    int sp = s - (DCONV - 1) + k;
    if (sp >= 0) {
      bf16x2 v = *(const bf16x2*)((const __hip_bfloat16*)src + (ptrdiff_t)(k - (DCONV - 1)) * (2 * DI));
      acc0 += cw[d0 * DCONV + k] * (float)v[0];
      acc1 += cw[(d0 + 1) * DCONV + k] * (float)v[1];
    }
  }
  bf16x2 o;
  o[0] = (__bf16)(acc0 * fsigmoid(acc0));
  o[1] = (__bf16)(acc1 * fsigmoid(acc1));
  *(bf16x2*)(xc + (size_t)t * DI + d0) = o;
}

// Bmat[t][n] = sum_k xc[t][k] * xpWt[n][k]   (n<16). 16 tokens per block.
__global__ void bmat_kernel(const __hip_bfloat16* __restrict__ xc,
                            const __hip_bfloat16* __restrict__ xpWt,
                            float* __restrict__ Bm) {
  int tid = threadIdx.x;
  int lane = tid & 63, wave = tid >> 6;
  int n = lane & 15, tsub = lane >> 4;
  int t = blockIdx.x * 16 + wave * 4 + tsub;
  const bf16x8* xr = (const bf16x8*)(xc + (size_t)t * DI);
  const bf16x8* wr = (const bf16x8*)(xpWt + (size_t)n * DI);
  float acc = 0.f;
#pragma unroll 4
  for (int k = 0; k < DI / 8; ++k) {
    bf16x8 a = xr[k], b = wr[k];
#pragma unroll
    for (int j = 0; j < 8; ++j) acc += (float)a[j] * (float)b[j];
  }
  Bm[(size_t)t * DSTATE + n] = acc;
}

// SSM pointwise: dty holds dtlin (bf16) in, y*silu(z) (bf16) out (in-place).
// A2 = -exp(A_log)*log2e  ->  dA term = exp2(A2*dt).
__global__ void ssm_kernel(const __hip_bfloat16* __restrict__ xc,
                           __hip_bfloat16* __restrict__ dty,
                           const float* __restrict__ Bm, const float* __restrict__ A2,
                           const float* __restrict__ dtb, const float* __restrict__ Dp,
                           const __hip_bfloat16* __restrict__ xz) {
  int t = blockIdx.x;
  __shared__ float Bs[DSTATE];
  if (threadIdx.x < DSTATE) Bs[threadIdx.x] = Bm[(size_t)t * DSTATE + threadIdx.x];
  __syncthreads();
  int d0 = threadIdx.x * 2;
  size_t idx = (size_t)t * DI + d0;
  bf16x2 dv = *(const bf16x2*)(dty + idx);
  bf16x2 xv = *(const bf16x2*)(xc + idx);
  bf16x2 zv2 = *(const bf16x2*)(xz + (size_t)t * (2 * DI) + DI + d0);
  bf16x2 o;
#pragma unroll
  for (int e = 0; e < 2; ++e) {
    int d = d0 + e;
    float dt = fsoftplus((float)dv[e] + dtb[d]);
    const f32x4* Ar = (const f32x4*)(A2 + d * DSTATE);
    float sdot = 0.f;
#pragma unroll
    for (int q = 0; q < 4; ++q) {
      f32x4 a = Ar[q];
#pragma unroll
      for (int j = 0; j < 4; ++j) sdot += fexp2(a[j] * dt) * Bs[q * 4 + j];
    }
    float xcv = (float)xv[e];
    float y = dt * xcv * sdot + Dp[d] * xcv;
    float z = (float)zv2[e];
    o[e] = (__bf16)(y * z * fsigmoid(z));
  }
  *(bf16x2*)(dty + idx) = o;
}

// x = rmsnorm(yout + x) * nw ; also refresh xb (bf16 copy)
__global__ void add_rmsnorm_kernel(const float* __restrict__ yout, float* __restrict__ x,
                                   const float* __restrict__ nw,
                                   __hip_bfloat16* __restrict__ xb) {
  int t = blockIdx.x;
  int c = threadIdx.x;
  size_t idx = (size_t)t * DM + c;
  float v = yout[idx] + x[idx];
  float sq = v * v;
#pragma unroll
  for (int off = 32; off > 0; off >>= 1) sq += __shfl_down(sq, off);
  __shared__ float sm[4];
  int wave = c >> 6, lane = c & 63;
  if (lane == 0) sm[wave] = sq;
  __syncthreads();
  float ms = (sm[0] + sm[1] + sm[2] + sm[3]) * (1.f / DM);
  float rr = rsqrtf(ms + RMS_EPS);
  float o = v * rr * nw[c];
  x[idx] = o;
  xb[idx] = __float2bfloat16(o);
}

// normalized entropy, single pass: H = lnS - T/S where S=sum e, T=sum e*(l-m)
__global__ void entropy_kernel(const float* __restrict__ logits, float* __restrict__ ent) {
  int t = blockIdx.x;
  int c = threadIdx.x;
  float l = logits[(size_t)t * VOCAB + c];
  int wave = c >> 6, lane = c & 63;
  __shared__ float sm[4], sm2[4];
  float m = l;
#pragma unroll
  for (int off = 32; off > 0; off >>= 1) m = fmaxf(m, __shfl_down(m, off));
  if (lane == 0) sm[wave] = m;
  __syncthreads();
  m = fmaxf(fmaxf(sm[0], sm[1]), fmaxf(sm[2], sm[3]));
  __syncthreads();
  float lm = l - m;
  float e = fexp(lm);
  float s = e, u = e * lm;
#pragma unroll
  for (int off = 32; off > 0; off >>= 1) {
    s += __shfl_down(s, off);
    u += __shfl_down(u, off);
  }
  if (lane == 0) { sm[wave] = s; sm2[wave] = u; }
  __syncthreads();
  if (c == 0) {
    s = sm[0] + sm[1] + sm[2] + sm[3];
    u = sm2[0] + sm2[1] + sm2[2] + sm2[3];
    ent[t] = (flog(s) - u * frcp(s)) * (1.f / LOG_VOCAB);
  }
}

// boundary scan + byte_to_patch + patch starts. 1 block, 8 waves (1 per batch).
__global__ void scan_kernel(const float* __restrict__ ent, float* __restrict__ btp_out,
                            int* __restrict__ btp_i, int* __restrict__ pstart,
                            int* __restrict__ npatch) {
  __shared__ unsigned long long masks[BB][32];
  __shared__ int wpre[BB][33];
  int tid = threadIdx.x;
  int w = tid >> 6, lane = tid & 63;
  int b = w;
  int size = 1;
  for (int w64 = 0; w64 < 32; ++w64) {
    int s = w64 * 64 + lane;
    float e = ent[b * SS + s];
    unsigned long long cb = __ballot(e > 0.5f);
    if (lane == 0) {
      unsigned long long bits;
      if (w64 == 0) {
        bits = 1ull;
        for (int j = 1; j < 64; ++j) {
          int c = (int)((cb >> j) & 1ull);
          int nb = c | (size >= 8);
          size = nb ? 1 : size + 1;
          bits |= ((unsigned long long)nb) << j;
        }
      } else if (cb == ~0ull) {
        bits = cb;
        size = 1;
      } else {
        bits = 0ull;
        for (int j = 0; j < 64; ++j) {
          int c = (int)((cb >> j) & 1ull);
          int nb = c | (size >= 8);
          size = nb ? 1 : size + 1;
          bits |= ((unsigned long long)nb) << j;
        }
      }
      masks[w][w64] = bits;
    }
  }
  __syncthreads();
  if (lane == 0) {
    int acc = 0;
    for (int i = 0; i < 32; ++i) {
      wpre[w][i] = acc;
      acc += __popcll(masks[w][i]);
    }
    wpre[w][32] = acc;
    npatch[b] = acc;
  }
  __syncthreads();
  for (int w64 = 0; w64 < 32; ++w64) {
    int s = w64 * 64 + lane;
    unsigned long long word = masks[w][w64];
    unsigned long long below =
        word & ((lane == 63) ? ~0ull : ((1ull << (lane + 1)) - 1ull));
    int btp = wpre[w][w64] + __popcll(below) - 1;
    btp_out[b * SS + s] = (float)btp;
    btp_i[b * SS + s] = btp;
    if ((word >> lane) & 1ull) pstart[b * SS + btp] = s;
  }
}

// per-patch mean pooling (contiguous ranges), zero-fill padding patches
__global__ void patch_kernel(const float* __restrict__ bemb, const int* __restrict__ pstart,
                             const int* __restrict__ npatch, float* __restrict__ pe_out,
                             float* __restrict__ plen_out) {
  int bp = blockIdx.x;
  int b = bp >> 11;
  int p = bp & (SS - 1);
  int c = threadIdx.x;
  int np = npatch[b];
  size_t outidx = (size_t)bp * DM + c;
  if (p >= np) {
    pe_out[outidx] = 0.f;
    if (c == 0) plen_out[bp] = 0.f;
    return;
  }
  int start = pstart[b * SS + p];
  int end = (p + 1 < np) ? pstart[b * SS + p + 1] : SS;
  float acc = 0.f;
  for (int t = start; t < end; ++t) acc += bemb[((size_t)b * SS + t) * DM + c];
  pe_out[outidx] = acc * frcp((float)(end - start));
  if (c == 0) plen_out[bp] = (float)(end - start);
}

// ---------------------------------------------------------------------------
// Launcher
// ---------------------------------------------------------------------------
template <typename OutT>
static inline void launch_gemm(const __hip_bfloat16* A, const __hip_bfloat16* Bt, OutT* C,
                               int M, int N, int K, hipStream_t stream) {
  dim3 grid(N / 128, M / 128);
  gemm_mfma<OutT><<<grid, 256, 0, stream>>>((const __bf16*)A, (const __bf16*)Bt, C, M, N, K);
}

extern "C" void kernel_launch(void* const* d_in, const int* in_sizes, int n_in,
                              void* d_out, int out_size, void* d_ws, size_t ws_size,
                              hipStream_t stream) {
  const int* bytes = (const int*)d_in[0];
  const float* bemb = (const float*)d_in[1];
  const float* embed_w = (const float*)d_in[2];
  const float* in_proj_w = (const float*)d_in[3];
  const float* conv_w = (const float*)d_in[4];
  const float* conv_b = (const float*)d_in[5];
  const float* x_proj_w = (const float*)d_in[6];
  const float* dt_w = (const float*)d_in[7];
  const float* dt_b = (const float*)d_in[8];
  const float* A_log = (const float*)d_in[9];
  const float* D_param = (const float*)d_in[10];
  const float* out_w = (const float*)d_in[11];
  const float* norm_w = (const float*)d_in[12];
  const float* head_w = (const float*)d_in[13];

  float* out = (float*)d_out;
  float* pe_out = out;                      // (B,S,DM)
  float* plen_out = out + (size_t)TT * DM;  // (B,S)
  float* btp_out = plen_out + TT;           // (B,S)

  char* wsb = (char*)d_ws;
  size_t off = 0;
  auto alloc = [&](size_t bytes) -> void* {
    void* p = wsb + off;
    off += (bytes + 255) & ~(size_t)255;
    return p;
  };
  float* A2 = (float*)alloc((size_t)NLAYERS * DI * DSTATE * 4);
  float* x = (float*)alloc((size_t)TT * DM * 4);
  __hip_bfloat16* xb = (__hip_bfloat16*)alloc((size_t)TT * DM * 2);
  __hip_bfloat16* xz = (__hip_bfloat16*)alloc((size_t)TT * 2 * DI * 2);
  __hip_bfloat16* xc = (__hip_bfloat16*)alloc((size_t)TT * DI * 2);
  __hip_bfloat16* dty = (__hip_bfloat16*)alloc((size_t)TT * DI * 2);
  float* yl = (float*)alloc((size_t)TT * DM * 4);  // yout / logits
  float* Bm = (float*)alloc((size_t)TT * DSTATE * 4);
  float* ent = (float*)alloc((size_t)TT * 4);
  int* btp_i = (int*)alloc((size_t)TT * 4);
  int* pstart = (int*)alloc((size_t)TT * 4);
  int* npatch = (int*)alloc(256);
  __hip_bfloat16* inWt = (__hip_bfloat16*)alloc((size_t)NLAYERS * 2 * DI * DM * 2);
  __hip_bfloat16* dtWt = (__hip_bfloat16*)alloc((size_t)NLAYERS * DI * DI * 2);
  __hip_bfloat16* oWt = (__hip_bfloat16*)alloc((size_t)NLAYERS * DM * DI * 2);
  __hip_bfloat16* xpWt = (__hip_bfloat16*)alloc((size_t)NLAYERS * 32 * DI * 2);
  __hip_bfloat16* headWt = (__hip_bfloat16*)alloc((size_t)VOCAB * DM * 2);

  // ---- weight prep ----
  aneg_kernel<<<(NLAYERS * DI * DSTATE + 255) / 256, 256, 0, stream>>>(
      A_log, A2, NLAYERS * DI * DSTATE);
  for (int l = 0; l < NLAYERS; ++l) {
    tcast_kernel<<<(DM * 2 * DI + 255) / 256, 256, 0, stream>>>(
        in_proj_w + (size_t)l * DM * 2 * DI, inWt + (size_t)l * 2 * DI * DM, DM, 2 * DI);
    tcast_kernel<<<(DI * DI + 255) / 256, 256, 0, stream>>>(
        dt_w + (size_t)l * DI * DI, dtWt + (size_t)l * DI * DI, DI, DI);
    tcast_kernel<<<(DI * DM + 255) / 256, 256, 0, stream>>>(
        out_w + (size_t)l * DI * DM, oWt + (size_t)l * DM * DI, DI, DM);
    tcast_kernel<<<(DI * 32 + 255) / 256, 256, 0, stream>>>(
        x_proj_w + (size_t)l * DI * 32, xpWt + (size_t)l * 32 * DI, DI, 32);
  }
  tcast_kernel<<<(DM * VOCAB + 255) / 256, 256, 0, stream>>>(head_w, headWt, DM, VOCAB);

  // ---- entropy model ----
  embed_kernel<<<TT, DM, 0, stream>>>(bytes, embed_w, x, xb);

  for (int l = 0; l < NLAYERS; ++l) {
    const float* cw = conv_w + (size_t)l * DI * DCONV;
    const float* cb = conv_b + (size_t)l * DI;
    const float* dtB = dt_b + (size_t)l * DI;
    const float* An = A2 + (size_t)l * DI * DSTATE;
    const float* Dp = D_param + (size_t)l * DI;
    const float* nW = norm_w + (size_t)l * DM;

    launch_gemm(xb, inWt + (size_t)l * 2 * DI * DM, (__hip_bfloat16*)xz, TT, 2 * DI, DM, stream);
    conv_silu_kernel<<<TT, 256, 0, stream>>>(xz, cw, cb, xc);
    bmat_kernel<<<TT / 16, 256, 0, stream>>>(xc, xpWt + (size_t)l * 32 * DI, Bm);
    launch_gemm(xc, dtWt + (size_t)l * DI * DI, dty, TT, DI, DI, stream);
    ssm_kernel<<<TT, 256, 0, stream>>>(xc, dty, Bm, An, dtB, Dp, xz);
    launch_gemm(dty, oWt + (size_t)l * DM * DI, yl, TT, DM, DI, stream);
    add_rmsnorm_kernel<<<TT, DM, 0, stream>>>(yl, x, nW, xb);
  }

  launch_gemm(xb, headWt, yl, TT, VOCAB, DM, stream);
  entropy_kernel<<<TT, VOCAB, 0, stream>>>(yl, ent);

  scan_kernel<<<1, 512, 0, stream>>>(ent, btp_out, btp_i, pstart, npatch);

  patch_kernel<<<TT, DM, 0, stream>>>(bemb, pstart, npatch, pe_out, plen_out);
}

// Round 4
// 429.420 us; speedup vs baseline: 1.5372x; 1.5372x over previous
//
#include <hip/hip_runtime.h>
#include <hip/hip_bf16.h>
#include <math.h>

// Problem constants
#define BB 8
#define SS 2048
#define TT (BB * SS)      // 16384 tokens
#define DM 256
#define DI 512
#define DSTATE 16
#define DCONV 4
#define NLAYERS 2
#define VOCAB 256
#define LOG_VOCAB 5.545177444479562f
#define RMS_EPS 1.1920929e-07f
#define LOG2E 1.4426950408889634f
#define LN2 0.6931471805599453f

typedef __attribute__((ext_vector_type(8))) __bf16 bf16x8;
typedef __attribute__((ext_vector_type(4))) __bf16 bf16x4;
typedef __attribute__((ext_vector_type(2))) __bf16 bf16x2;
typedef __attribute__((ext_vector_type(4))) float f32x4;

// ---- fast transcendentals (1-ulp class; entropy margin vs THR=0.5 is ~0.4) ----
__device__ __forceinline__ float fexp(float x) { return __builtin_amdgcn_exp2f(x * LOG2E); }
__device__ __forceinline__ float fexp2(float x) { return __builtin_amdgcn_exp2f(x); }
__device__ __forceinline__ float flog(float x) { return __builtin_amdgcn_logf(x) * LN2; }
__device__ __forceinline__ float frcp(float x) { return __builtin_amdgcn_rcpf(x); }
__device__ __forceinline__ float fsigmoid(float x) { return frcp(1.f + fexp(-x)); }
__device__ __forceinline__ float fsoftplus(float x) {
  return fmaxf(x, 0.f) + flog(1.f + fexp(-fabsf(x)));
}

// ---------------------------------------------------------------------------
// bf16 MFMA GEMM (m97 structure): C[M,N] = A[M,K] @ Bt[N,K]^T
// ---------------------------------------------------------------------------
__device__ __forceinline__ void gl2lds16(const void* g, void* l) {
  __builtin_amdgcn_global_load_lds(
      (const __attribute__((address_space(1))) void*)g,
      (__attribute__((address_space(3))) void*)l, 16, 0, 0);
}

template <typename T> __device__ __forceinline__ T cvt_out(float v);
template <> __device__ __forceinline__ float cvt_out<float>(float v) { return v; }
template <> __device__ __forceinline__ __hip_bfloat16 cvt_out<__hip_bfloat16>(float v) {
  return __float2bfloat16(v);
}

template <typename OutT>
__global__ __launch_bounds__(256) void gemm_mfma(
    const __bf16* __restrict__ A,   // [M][K]
    const __bf16* __restrict__ Bt,  // [N][K]  (W^T)
    OutT* __restrict__ C,           // [M][N]
    int M, int N, int K) {
  __shared__ __align__(16) __bf16 As[128 * 32];
  __shared__ __align__(16) __bf16 Bs[128 * 32];
  int tid = threadIdx.x;
  int lane = tid & 63;
  int wave = tid >> 6;
  int wm = (wave & 1) * 64;
  int wn = (wave >> 1) * 64;
  int m0 = blockIdx.y * 128;
  int n0 = blockIdx.x * 128;

  int r = tid >> 2;
  int kc = (tid & 3) * 8;
  int fr = lane & 15;
  int fk = (lane >> 4) * 8;

  f32x4 acc[4][4] = {};

  for (int k0 = 0; k0 < K; k0 += 32) {
    gl2lds16(A + (size_t)(m0 + r) * K + k0 + kc, As + r * 32 + kc);
    gl2lds16(A + (size_t)(m0 + 64 + r) * K + k0 + kc, As + (64 + r) * 32 + kc);
    gl2lds16(Bt + (size_t)(n0 + r) * K + k0 + kc, Bs + r * 32 + kc);
    gl2lds16(Bt + (size_t)(n0 + 64 + r) * K + k0 + kc, Bs + (64 + r) * 32 + kc);
    __syncthreads();

    bf16x8 af[4], bfr[4];
#pragma unroll
    for (int i = 0; i < 4; ++i) {
      af[i] = *(const bf16x8*)(As + (wm + i * 16 + fr) * 32 + fk);
      bfr[i] = *(const bf16x8*)(Bs + (wn + i * 16 + fr) * 32 + fk);
    }
#pragma unroll
    for (int i = 0; i < 4; ++i)
#pragma unroll
      for (int j = 0; j < 4; ++j)
        acc[i][j] = __builtin_amdgcn_mfma_f32_16x16x32_bf16(af[i], bfr[j], acc[i][j], 0, 0, 0);
    __syncthreads();
  }

  int cr = (lane >> 4) * 4;
  int cc = lane & 15;
#pragma unroll
  for (int i = 0; i < 4; ++i) {
    int mrow = m0 + wm + i * 16 + cr;
#pragma unroll
    for (int j = 0; j < 4; ++j) {
      int ncol = n0 + wn + j * 16 + cc;
#pragma unroll
      for (int rg = 0; rg < 4; ++rg)
        C[(size_t)(mrow + rg) * N + ncol] = cvt_out<OutT>(acc[i][j][rg]);
    }
  }
}

// ---------------------------------------------------------------------------
// Merged weight prep: all transposes/casts + A2 in ONE dispatch.
// dst[n*K+k] = bf16(src[k*N+n])
// ---------------------------------------------------------------------------
__device__ __forceinline__ void tcast_seg(const float* __restrict__ src,
                                          __hip_bfloat16* __restrict__ dst,
                                          int i, int K, int N) {
  int n = i / K, k = i - n * K;
  dst[i] = __float2bfloat16(src[(size_t)k * N + n]);
}

#define PREP_TOTAL (16384 + 65536 + 2 * (262144 + 262144 + 131072 + 16384))

__global__ void prep_kernel(const float* __restrict__ A_log, float* __restrict__ A2,
                            const float* __restrict__ head_w, __hip_bfloat16* __restrict__ headWt,
                            const float* __restrict__ in_proj_w, __hip_bfloat16* __restrict__ inWt,
                            const float* __restrict__ dt_w, __hip_bfloat16* __restrict__ dtWt,
                            const float* __restrict__ out_w, __hip_bfloat16* __restrict__ oWt,
                            const float* __restrict__ x_proj_w, __hip_bfloat16* __restrict__ xpWt) {
  int i = blockIdx.x * 256 + threadIdx.x;
  if (i >= PREP_TOTAL) return;
  if (i < 16384) { A2[i] = -fexp(A_log[i]) * LOG2E; return; }
  i -= 16384;
  if (i < 65536) { tcast_seg(head_w, headWt, i, 256, 256); return; }
  i -= 65536;
  int l = i / 671744;
  i -= l * 671744;
  if (i < 262144) { tcast_seg(in_proj_w + (size_t)l * 262144, inWt + (size_t)l * 262144, i, 256, 1024); return; }
  i -= 262144;
  if (i < 262144) { tcast_seg(dt_w + (size_t)l * 262144, dtWt + (size_t)l * 262144, i, 512, 512); return; }
  i -= 262144;
  if (i < 131072) { tcast_seg(out_w + (size_t)l * 131072, oWt + (size_t)l * 131072, i, 512, 256); return; }
  i -= 131072;
  tcast_seg(x_proj_w + (size_t)l * 16384, xpWt + (size_t)l * 16384, i, 512, 32);
}

// embedding gather -> x fp32 + xb bf16
__global__ void embed_kernel(const int* __restrict__ bytes, const float* __restrict__ ew,
                             float* __restrict__ x, __hip_bfloat16* __restrict__ xb) {
  int t = blockIdx.x;
  int c = threadIdx.x;
  float v = ew[(size_t)bytes[t] * DM + c];
  x[(size_t)t * DM + c] = v;
  xb[(size_t)t * DM + c] = __float2bfloat16(v);
}

// ---------------------------------------------------------------------------
// Sliding-window causal depthwise conv + bias + silu.
// Each thread owns 2 channels for a 16-token chunk; taps in registers;
// every x_in element read exactly once. grid = BB * (SS/16) = 1024 blocks.
// ---------------------------------------------------------------------------
#define CV_CHUNK 16
__global__ __launch_bounds__(256) void conv_silu_kernel(
    const __hip_bfloat16* __restrict__ xz, const float* __restrict__ cw,
    const float* __restrict__ cb, __hip_bfloat16* __restrict__ xc) {
  int blk = blockIdx.x;
  int b = blk >> 7;
  int s0 = (blk & 127) * CV_CHUNK;
  int d0 = threadIdx.x * 2;
  float w0[4], w1[4];
#pragma unroll
  for (int k = 0; k < 4; ++k) {
    w0[k] = cw[d0 * 4 + k];
    w1[k] = cw[(d0 + 1) * 4 + k];
  }
  float b0 = cb[d0], b1 = cb[d0 + 1];
  const __hip_bfloat16* base = xz + (size_t)b * SS * 1024 + d0;
  float h0x = 0, h0y = 0, h1x = 0, h1y = 0, h2x = 0, h2y = 0;
  if (s0 > 0) {  // halo (s0>=16 here, so all three in-bounds)
    bf16x2 p0 = *(const bf16x2*)(base + (size_t)(s0 - 3) * 1024);
    bf16x2 p1 = *(const bf16x2*)(base + (size_t)(s0 - 2) * 1024);
    bf16x2 p2 = *(const bf16x2*)(base + (size_t)(s0 - 1) * 1024);
    h0x = (float)p0[0]; h0y = (float)p0[1];
    h1x = (float)p1[0]; h1y = (float)p1[1];
    h2x = (float)p2[0]; h2y = (float)p2[1];
  }
#pragma unroll
  for (int s = 0; s < CV_CHUNK; ++s) {
    bf16x2 cur = *(const bf16x2*)(base + (size_t)(s0 + s) * 1024);
    float cx = (float)cur[0], cy = (float)cur[1];
    float acc0 = b0 + w0[0] * h0x + w0[1] * h1x + w0[2] * h2x + w0[3] * cx;
    float acc1 = b1 + w1[0] * h0y + w1[1] * h1y + w1[2] * h2y + w1[3] * cy;
    bf16x2 o;
    o[0] = (__bf16)(acc0 * fsigmoid(acc0));
    o[1] = (__bf16)(acc1 * fsigmoid(acc1));
    *(bf16x2*)(xc + ((size_t)b * SS + s0 + s) * DI + d0) = o;
    h0x = h1x; h1x = h2x; h2x = cx;
    h0y = h1y; h1y = h2y; h2y = cy;
  }
}

// Bmat[t][n] = sum_k xc[t][k] * xpWt[n][k]   (n<16). 16 tokens per block.
__global__ void bmat_kernel(const __hip_bfloat16* __restrict__ xc,
                            const __hip_bfloat16* __restrict__ xpWt,
                            float* __restrict__ Bm) {
  int tid = threadIdx.x;
  int lane = tid & 63, wave = tid >> 6;
  int n = lane & 15, tsub = lane >> 4;
  int t = blockIdx.x * 16 + wave * 4 + tsub;
  const bf16x8* xr = (const bf16x8*)(xc + (size_t)t * DI);
  const bf16x8* wr = (const bf16x8*)(xpWt + (size_t)n * DI);
  float acc = 0.f;
#pragma unroll 4
  for (int k = 0; k < DI / 8; ++k) {
    bf16x8 a = xr[k], b = wr[k];
#pragma unroll
    for (int j = 0; j < 8; ++j) acc += (float)a[j] * (float)b[j];
  }
  Bm[(size_t)t * DSTATE + n] = acc;
}

// ---------------------------------------------------------------------------
// Persistent SSM pointwise: thread owns 2 fixed channels, A2/dtb/Dp in
// registers, loops over SSM_TOK tokens. Bm read as block-uniform loads
// (no LDS, no barrier). grid = TT / SSM_TOK.
// ---------------------------------------------------------------------------
#define SSM_TOK 8
__global__ __launch_bounds__(256) void ssm_kernel(
    const __hip_bfloat16* __restrict__ xc, __hip_bfloat16* __restrict__ dty,
    const float* __restrict__ Bm, const float* __restrict__ A2,
    const float* __restrict__ dtb, const float* __restrict__ Dp,
    const __hip_bfloat16* __restrict__ xz) {
  int d0 = threadIdx.x * 2;
  int t0 = blockIdx.x * SSM_TOK;
  f32x4 a0[4], a1[4];
#pragma unroll
  for (int q = 0; q < 4; ++q) {
    a0[q] = *(const f32x4*)(A2 + d0 * 16 + q * 4);
    a1[q] = *(const f32x4*)(A2 + (d0 + 1) * 16 + q * 4);
  }
  float dtb0 = dtb[d0], dtb1 = dtb[d0 + 1];
  float dp0 = Dp[d0], dp1 = Dp[d0 + 1];
#pragma unroll
  for (int i = 0; i < SSM_TOK; ++i) {
    int t = t0 + i;
    const f32x4* br = (const f32x4*)(Bm + (size_t)t * DSTATE);
    f32x4 Bq[4];
#pragma unroll
    for (int q = 0; q < 4; ++q) Bq[q] = br[q];
    size_t idx = (size_t)t * DI + d0;
    bf16x2 dv = *(const bf16x2*)(dty + idx);
    bf16x2 xv = *(const bf16x2*)(xc + idx);
    bf16x2 zv = *(const bf16x2*)(xz + (size_t)t * 1024 + DI + d0);
    float dt0 = fsoftplus((float)dv[0] + dtb0);
    float dt1 = fsoftplus((float)dv[1] + dtb1);
    float s0 = 0.f, s1 = 0.f;
#pragma unroll
    for (int q = 0; q < 4; ++q)
#pragma unroll
      for (int j = 0; j < 4; ++j) {
        s0 += fexp2(a0[q][j] * dt0) * Bq[q][j];
        s1 += fexp2(a1[q][j] * dt1) * Bq[q][j];
      }
    float x0 = (float)xv[0], x1 = (float)xv[1];
    float y0 = dt0 * x0 * s0 + dp0 * x0;
    float y1 = dt1 * x1 * s1 + dp1 * x1;
    float z0 = (float)zv[0], z1 = (float)zv[1];
    bf16x2 o;
    o[0] = (__bf16)(y0 * z0 * fsigmoid(z0));
    o[1] = (__bf16)(y1 * z1 * fsigmoid(z1));
    *(bf16x2*)(dty + idx) = o;
  }
}

// x = rmsnorm(yout + x) * nw ; refresh xb. Wave-per-token, float4 per lane.
// grid = TT/4, block 256 (4 waves).
__global__ __launch_bounds__(256) void add_rmsnorm_kernel(
    const float* __restrict__ yout, float* __restrict__ x,
    const float* __restrict__ nw, __hip_bfloat16* __restrict__ xb) {
  int wv = threadIdx.x >> 6, lane = threadIdx.x & 63;
  int t = blockIdx.x * 4 + wv;
  size_t row = (size_t)t * DM;
  int c = lane * 4;
  f32x4 yv = *(const f32x4*)(yout + row + c);
  f32x4 xv = *(const f32x4*)(x + row + c);
  f32x4 v = yv + xv;
  float sq = v[0] * v[0] + v[1] * v[1] + v[2] * v[2] + v[3] * v[3];
#pragma unroll
  for (int off = 32; off > 0; off >>= 1) sq += __shfl_xor(sq, off);
  float r = rsqrtf(sq * (1.f / DM) + RMS_EPS);
  f32x4 w = *(const f32x4*)(nw + c);
  f32x4 o;
#pragma unroll
  for (int j = 0; j < 4; ++j) o[j] = v[j] * r * w[j];
  *(f32x4*)(x + row + c) = o;
  bf16x4 ob;
#pragma unroll
  for (int j = 0; j < 4; ++j) ob[j] = (__bf16)o[j];
  *(bf16x4*)(xb + row + c) = ob;
}

// normalized entropy, wave-per-token, single pass: H = lnS - T/S.
// grid = TT/4, block 256 (4 waves).
__global__ __launch_bounds__(256) void entropy_kernel(const float* __restrict__ logits,
                                                      float* __restrict__ ent) {
  int wv = threadIdx.x >> 6, lane = threadIdx.x & 63;
  int t = blockIdx.x * 4 + wv;
  f32x4 l = *(const f32x4*)(logits + (size_t)t * VOCAB + lane * 4);
  float m = fmaxf(fmaxf(l[0], l[1]), fmaxf(l[2], l[3]));
#pragma unroll
  for (int off = 32; off > 0; off >>= 1) m = fmaxf(m, __shfl_xor(m, off));
  float s = 0.f, u = 0.f;
#pragma unroll
  for (int j = 0; j < 4; ++j) {
    float lm = l[j] - m;
    float e = fexp(lm);
    s += e;
    u += e * lm;
  }
#pragma unroll
  for (int off = 32; off > 0; off >>= 1) {
    s += __shfl_xor(s, off);
    u += __shfl_xor(u, off);
  }
  if (lane == 0) ent[t] = (flog(s) - u * frcp(s)) * (1.f / LOG_VOCAB);
}

// boundary scan + byte_to_patch + patch starts. 1 block, 8 waves (1 per batch).
__global__ void scan_kernel(const float* __restrict__ ent, float* __restrict__ btp_out,
                            int* __restrict__ btp_i, int* __restrict__ pstart,
                            int* __restrict__ npatch) {
  __shared__ unsigned long long masks[BB][32];
  __shared__ int wpre[BB][33];
  int tid = threadIdx.x;
  int w = tid >> 6, lane = tid & 63;
  int b = w;
  int size = 1;
  for (int w64 = 0; w64 < 32; ++w64) {
    int s = w64 * 64 + lane;
    float e = ent[b * SS + s];
    unsigned long long cb = __ballot(e > 0.5f);
    if (lane == 0) {
      unsigned long long bits;
      if (w64 == 0) {
        bits = 1ull;
        for (int j = 1; j < 64; ++j) {
          int c = (int)((cb >> j) & 1ull);
          int nb = c | (size >= 8);
          size = nb ? 1 : size + 1;
          bits |= ((unsigned long long)nb) << j;
        }
      } else if (cb == ~0ull) {
        bits = cb;
        size = 1;
      } else {
        bits = 0ull;
        for (int j = 0; j < 64; ++j) {
          int c = (int)((cb >> j) & 1ull);
          int nb = c | (size >= 8);
          size = nb ? 1 : size + 1;
          bits |= ((unsigned long long)nb) << j;
        }
      }
      masks[w][w64] = bits;
    }
  }
  __syncthreads();
  if (lane == 0) {
    int acc = 0;
    for (int i = 0; i < 32; ++i) {
      wpre[w][i] = acc;
      acc += __popcll(masks[w][i]);
    }
    wpre[w][32] = acc;
    npatch[b] = acc;
  }
  __syncthreads();
  for (int w64 = 0; w64 < 32; ++w64) {
    int s = w64 * 64 + lane;
    unsigned long long word = masks[w][w64];
    unsigned long long below =
        word & ((lane == 63) ? ~0ull : ((1ull << (lane + 1)) - 1ull));
    int btp = wpre[w][w64] + __popcll(below) - 1;
    btp_out[b * SS + s] = (float)btp;
    btp_i[b * SS + s] = btp;
    if ((word >> lane) & 1ull) pstart[b * SS + btp] = s;
  }
}

// per-patch mean pooling (contiguous ranges), zero-fill padding patches
__global__ void patch_kernel(const float* __restrict__ bemb, const int* __restrict__ pstart,
                             const int* __restrict__ npatch, float* __restrict__ pe_out,
                             float* __restrict__ plen_out) {
  int bp = blockIdx.x;
  int b = bp >> 11;
  int p = bp & (SS - 1);
  int c = threadIdx.x;
  int np = npatch[b];
  size_t outidx = (size_t)bp * DM + c;
  if (p >= np) {
    pe_out[outidx] = 0.f;
    if (c == 0) plen_out[bp] = 0.f;
    return;
  }
  int start = pstart[b * SS + p];
  int end = (p + 1 < np) ? pstart[b * SS + p + 1] : SS;
  float acc = 0.f;
  for (int t = start; t < end; ++t) acc += bemb[((size_t)b * SS + t) * DM + c];
  pe_out[outidx] = acc * frcp((float)(end - start));
  if (c == 0) plen_out[bp] = (float)(end - start);
}

// ---------------------------------------------------------------------------
// Launcher
// ---------------------------------------------------------------------------
template <typename OutT>
static inline void launch_gemm(const __hip_bfloat16* A, const __hip_bfloat16* Bt, OutT* C,
                               int M, int N, int K, hipStream_t stream) {
  dim3 grid(N / 128, M / 128);
  gemm_mfma<OutT><<<grid, 256, 0, stream>>>((const __bf16*)A, (const __bf16*)Bt, C, M, N, K);
}

extern "C" void kernel_launch(void* const* d_in, const int* in_sizes, int n_in,
                              void* d_out, int out_size, void* d_ws, size_t ws_size,
                              hipStream_t stream) {
  const int* bytes = (const int*)d_in[0];
  const float* bemb = (const float*)d_in[1];
  const float* embed_w = (const float*)d_in[2];
  const float* in_proj_w = (const float*)d_in[3];
  const float* conv_w = (const float*)d_in[4];
  const float* conv_b = (const float*)d_in[5];
  const float* x_proj_w = (const float*)d_in[6];
  const float* dt_w = (const float*)d_in[7];
  const float* dt_b = (const float*)d_in[8];
  const float* A_log = (const float*)d_in[9];
  const float* D_param = (const float*)d_in[10];
  const float* out_w = (const float*)d_in[11];
  const float* norm_w = (const float*)d_in[12];
  const float* head_w = (const float*)d_in[13];

  float* out = (float*)d_out;
  float* pe_out = out;                      // (B,S,DM)
  float* plen_out = out + (size_t)TT * DM;  // (B,S)
  float* btp_out = plen_out + TT;           // (B,S)

  char* wsb = (char*)d_ws;
  size_t off = 0;
  auto alloc = [&](size_t bytes) -> void* {
    void* p = wsb + off;
    off += (bytes + 255) & ~(size_t)255;
    return p;
  };
  float* A2 = (float*)alloc((size_t)NLAYERS * DI * DSTATE * 4);
  float* x = (float*)alloc((size_t)TT * DM * 4);
  __hip_bfloat16* xb = (__hip_bfloat16*)alloc((size_t)TT * DM * 2);
  __hip_bfloat16* xz = (__hip_bfloat16*)alloc((size_t)TT * 2 * DI * 2);
  __hip_bfloat16* xc = (__hip_bfloat16*)alloc((size_t)TT * DI * 2);
  __hip_bfloat16* dty = (__hip_bfloat16*)alloc((size_t)TT * DI * 2);
  float* yl = (float*)alloc((size_t)TT * DM * 4);  // yout / logits
  float* Bm = (float*)alloc((size_t)TT * DSTATE * 4);
  float* ent = (float*)alloc((size_t)TT * 4);
  int* btp_i = (int*)alloc((size_t)TT * 4);
  int* pstart = (int*)alloc((size_t)TT * 4);
  int* npatch = (int*)alloc(256);
  __hip_bfloat16* inWt = (__hip_bfloat16*)alloc((size_t)NLAYERS * 2 * DI * DM * 2);
  __hip_bfloat16* dtWt = (__hip_bfloat16*)alloc((size_t)NLAYERS * DI * DI * 2);
  __hip_bfloat16* oWt = (__hip_bfloat16*)alloc((size_t)NLAYERS * DM * DI * 2);
  __hip_bfloat16* xpWt = (__hip_bfloat16*)alloc((size_t)NLAYERS * 32 * DI * 2);
  __hip_bfloat16* headWt = (__hip_bfloat16*)alloc((size_t)VOCAB * DM * 2);

  // ---- weight prep (single dispatch) ----
  prep_kernel<<<(PREP_TOTAL + 255) / 256, 256, 0, stream>>>(
      A_log, A2, head_w, headWt, in_proj_w, inWt, dt_w, dtWt, out_w, oWt, x_proj_w, xpWt);

  // ---- entropy model ----
  embed_kernel<<<TT, DM, 0, stream>>>(bytes, embed_w, x, xb);

  for (int l = 0; l < NLAYERS; ++l) {
    const float* cw = conv_w + (size_t)l * DI * DCONV;
    const float* cb = conv_b + (size_t)l * DI;
    const float* dtB = dt_b + (size_t)l * DI;
    const float* An = A2 + (size_t)l * DI * DSTATE;
    const float* Dp = D_param + (size_t)l * DI;
    const float* nW = norm_w + (size_t)l * DM;

    launch_gemm(xb, inWt + (size_t)l * 2 * DI * DM, (__hip_bfloat16*)xz, TT, 2 * DI, DM, stream);
    conv_silu_kernel<<<BB * (SS / CV_CHUNK), 256, 0, stream>>>(xz, cw, cb, xc);
    bmat_kernel<<<TT / 16, 256, 0, stream>>>(xc, xpWt + (size_t)l * 32 * DI, Bm);
    launch_gemm(xc, dtWt + (size_t)l * DI * DI, dty, TT, DI, DI, stream);
    ssm_kernel<<<TT / SSM_TOK, 256, 0, stream>>>(xc, dty, Bm, An, dtB, Dp, xz);
    launch_gemm(dty, oWt + (size_t)l * DM * DI, yl, TT, DM, DI, stream);
    add_rmsnorm_kernel<<<TT / 4, 256, 0, stream>>>(yl, x, nW, xb);
  }

  launch_gemm(xb, headWt, yl, TT, VOCAB, DM, stream);
  entropy_kernel<<<TT / 4, 256, 0, stream>>>(yl, ent);

  scan_kernel<<<1, 512, 0, stream>>>(ent, btp_out, btp_i, pstart, npatch);

  patch_kernel<<<TT, DM, 0, stream>>>(bemb, pstart, npatch, pe_out, plen_out);
}

// Round 5
// 366.105 us; speedup vs baseline: 1.8030x; 1.1729x over previous
//
#include <hip/hip_runtime.h>
#include <hip/hip_bf16.h>
#include <math.h>

// Problem constants
#define BB 8
#define SS 2048
#define TT (BB * SS)      // 16384 tokens
#define DM 256
#define DI 512
#define DSTATE 16
#define DCONV 4
#define NLAYERS 2
#define VOCAB 256
#define LOG_VOCAB 5.545177444479562f
#define RMS_EPS 1.1920929e-07f
#define LOG2E 1.4426950408889634f
#define LN2 0.6931471805599453f

#define TW 64            // tokens per fused block
#define XST 520          // xcs LDS row stride (bf16 elems): 520*2=1040B -> 2-way bank aliasing only
#define BMST 20          // Bms LDS row stride (f32)

typedef __attribute__((ext_vector_type(8))) __bf16 bf16x8;
typedef __attribute__((ext_vector_type(4))) __bf16 bf16x4;
typedef __attribute__((ext_vector_type(2))) __bf16 bf16x2;
typedef __attribute__((ext_vector_type(4))) float f32x4;

// ---- fast transcendentals (1-ulp class; entropy margin vs THR=0.5 is ~0.4) ----
__device__ __forceinline__ float fexp(float x) { return __builtin_amdgcn_exp2f(x * LOG2E); }
__device__ __forceinline__ float fexp2(float x) { return __builtin_amdgcn_exp2f(x); }
__device__ __forceinline__ float flog(float x) { return __builtin_amdgcn_logf(x) * LN2; }
__device__ __forceinline__ float frcp(float x) { return __builtin_amdgcn_rcpf(x); }
__device__ __forceinline__ float fsigmoid(float x) { return frcp(1.f + fexp(-x)); }
__device__ __forceinline__ float fsoftplus(float x) {
  return fmaxf(x, 0.f) + flog(1.f + fexp(-fabsf(x)));
}

// ---------------------------------------------------------------------------
// bf16 MFMA GEMM (m97 structure): C[M,N] = A[M,K] @ Bt[N,K]^T  (in_proj only)
// ---------------------------------------------------------------------------
__device__ __forceinline__ void gl2lds16(const void* g, void* l) {
  __builtin_amdgcn_global_load_lds(
      (const __attribute__((address_space(1))) void*)g,
      (__attribute__((address_space(3))) void*)l, 16, 0, 0);
}

__global__ __launch_bounds__(256) void gemm_mfma(
    const __bf16* __restrict__ A,   // [M][K]
    const __bf16* __restrict__ Bt,  // [N][K]  (W^T)
    __hip_bfloat16* __restrict__ C, // [M][N]
    int M, int N, int K) {
  __shared__ __align__(16) __bf16 As[128 * 32];
  __shared__ __align__(16) __bf16 Bs[128 * 32];
  int tid = threadIdx.x;
  int lane = tid & 63;
  int wave = tid >> 6;
  int wm = (wave & 1) * 64;
  int wn = (wave >> 1) * 64;
  int m0 = blockIdx.y * 128;
  int n0 = blockIdx.x * 128;

  int r = tid >> 2;
  int kc = (tid & 3) * 8;
  int fr = lane & 15;
  int fk = (lane >> 4) * 8;

  f32x4 acc[4][4] = {};

  for (int k0 = 0; k0 < K; k0 += 32) {
    gl2lds16(A + (size_t)(m0 + r) * K + k0 + kc, As + r * 32 + kc);
    gl2lds16(A + (size_t)(m0 + 64 + r) * K + k0 + kc, As + (64 + r) * 32 + kc);
    gl2lds16(Bt + (size_t)(n0 + r) * K + k0 + kc, Bs + r * 32 + kc);
    gl2lds16(Bt + (size_t)(n0 + 64 + r) * K + k0 + kc, Bs + (64 + r) * 32 + kc);
    __syncthreads();

    bf16x8 af[4], bfr[4];
#pragma unroll
    for (int i = 0; i < 4; ++i) {
      af[i] = *(const bf16x8*)(As + (wm + i * 16 + fr) * 32 + fk);
      bfr[i] = *(const bf16x8*)(Bs + (wn + i * 16 + fr) * 32 + fk);
    }
#pragma unroll
    for (int i = 0; i < 4; ++i)
#pragma unroll
      for (int j = 0; j < 4; ++j)
        acc[i][j] = __builtin_amdgcn_mfma_f32_16x16x32_bf16(af[i], bfr[j], acc[i][j], 0, 0, 0);
    __syncthreads();
  }

  int cr = (lane >> 4) * 4;
  int cc = lane & 15;
#pragma unroll
  for (int i = 0; i < 4; ++i) {
    int mrow = m0 + wm + i * 16 + cr;
#pragma unroll
    for (int j = 0; j < 4; ++j) {
      int ncol = n0 + wn + j * 16 + cc;
#pragma unroll
      for (int rg = 0; rg < 4; ++rg)
        C[(size_t)(mrow + rg) * N + ncol] = __float2bfloat16(acc[i][j][rg]);
    }
  }
}

// ---------------------------------------------------------------------------
// Merged prep: weight transposes/casts + A2 + embedding gather, ONE dispatch.
// ---------------------------------------------------------------------------
__device__ __forceinline__ void tcast_seg(const float* __restrict__ src,
                                          __hip_bfloat16* __restrict__ dst,
                                          int i, int K, int N) {
  int n = i / K, k = i - n * K;
  dst[i] = __float2bfloat16(src[(size_t)k * N + n]);
}

#define PREP_TOTAL (16384 + 65536 + 2 * (262144 + 262144 + 131072 + 16384))
#define PREP_ALL (PREP_TOTAL + TT * DM)

__global__ void prep_kernel(const float* __restrict__ A_log, float* __restrict__ A2,
                            const float* __restrict__ head_w, __hip_bfloat16* __restrict__ headWt,
                            const float* __restrict__ in_proj_w, __hip_bfloat16* __restrict__ inWt,
                            const float* __restrict__ dt_w, __hip_bfloat16* __restrict__ dtWt,
                            const float* __restrict__ out_w, __hip_bfloat16* __restrict__ oWt,
                            const float* __restrict__ x_proj_w, __hip_bfloat16* __restrict__ xpWt,
                            const int* __restrict__ bytes, const float* __restrict__ embed_w,
                            float* __restrict__ x, __hip_bfloat16* __restrict__ xb) {
  int i = blockIdx.x * 256 + threadIdx.x;
  if (i >= PREP_ALL) return;
  if (i >= PREP_TOTAL) {  // embedding gather
    i -= PREP_TOTAL;
    int t = i >> 8, c = i & 255;
    float v = embed_w[(size_t)bytes[t] * DM + c];
    x[i] = v;
    xb[i] = __float2bfloat16(v);
    return;
  }
  if (i < 16384) { A2[i] = -fexp(A_log[i]) * LOG2E; return; }
  i -= 16384;
  if (i < 65536) { tcast_seg(head_w, headWt, i, 256, 256); return; }
  i -= 65536;
  int l = i / 671744;
  i -= l * 671744;
  if (i < 262144) { tcast_seg(in_proj_w + (size_t)l * 262144, inWt + (size_t)l * 262144, i, 256, 1024); return; }
  i -= 262144;
  if (i < 262144) { tcast_seg(dt_w + (size_t)l * 262144, dtWt + (size_t)l * 262144, i, 512, 512); return; }
  i -= 262144;
  if (i < 131072) { tcast_seg(out_w + (size_t)l * 131072, oWt + (size_t)l * 131072, i, 512, 256); return; }
  i -= 131072;
  tcast_seg(x_proj_w + (size_t)l * 16384, xpWt + (size_t)l * 16384, i, 512, 32);
}

// ---------------------------------------------------------------------------
// Fused Mamba layer (everything after in_proj): conv+silu -> bmat (MFMA)
// -> dt-GEMM (MFMA) -> ssm (in-register on acc) -> y (LDS) -> *silu(z)
// -> out-GEMM (MFMA) -> add-residual + rmsnorm -> x, xb.
// 64-token tile per block, grid = TT/64 = 256 blocks, 256 threads (4 waves).
// Dynamic LDS: xcs[64][520] bf16 + Bms[64][20] f32 + rmsp[64][4] f32 = 72,704 B.
// ---------------------------------------------------------------------------
__global__ __launch_bounds__(256) void mamba_fused(
    const __hip_bfloat16* __restrict__ xz,   // [TT][1024]: x_in | z
    const __bf16* __restrict__ dtW,          // [512][512]  W^T
    const __bf16* __restrict__ oW,           // [256][512]  W^T
    const __bf16* __restrict__ xpW,          // [32][512]   W^T (rows 0..15 = B)
    const float* __restrict__ cw, const float* __restrict__ cb,
    const float* __restrict__ A2, const float* __restrict__ dtb,
    const float* __restrict__ Dp, const float* __restrict__ nw,
    float* __restrict__ x, __hip_bfloat16* __restrict__ xb) {
  extern __shared__ char smem[];
  __bf16* xcs = (__bf16*)smem;                        // [64][XST]
  float* Bms = (float*)(smem + TW * XST * 2);         // [64][BMST]
  float* rmsp = Bms + TW * BMST;                      // [64][4]

  int tid = threadIdx.x;
  int lane = tid & 63;
  int w = tid >> 6;
  int quad = lane >> 4;
  int l15 = lane & 15;
  int t0 = blockIdx.x * TW;
  int s0 = t0 & (SS - 1);

  // ---- P0: causal depthwise conv + bias + silu -> xcs ----
  {
    int d0 = tid * 2;
    float w0[4], w1[4];
#pragma unroll
    for (int k = 0; k < 4; ++k) {
      w0[k] = cw[d0 * 4 + k];
      w1[k] = cw[(d0 + 1) * 4 + k];
    }
    float b0 = cb[d0], b1 = cb[d0 + 1];
    float h0x = 0, h0y = 0, h1x = 0, h1y = 0, h2x = 0, h2y = 0;
    if (s0 > 0) {
      bf16x2 p0 = *(const bf16x2*)(xz + (size_t)(t0 - 3) * 1024 + d0);
      bf16x2 p1 = *(const bf16x2*)(xz + (size_t)(t0 - 2) * 1024 + d0);
      bf16x2 p2 = *(const bf16x2*)(xz + (size_t)(t0 - 1) * 1024 + d0);
      h0x = (float)p0[0]; h0y = (float)p0[1];
      h1x = (float)p1[0]; h1y = (float)p1[1];
      h2x = (float)p2[0]; h2y = (float)p2[1];
    }
#pragma unroll 4
    for (int s = 0; s < TW; ++s) {
      bf16x2 cur = *(const bf16x2*)(xz + (size_t)(t0 + s) * 1024 + d0);
      float cx = (float)cur[0], cy = (float)cur[1];
      float a0 = b0 + w0[0] * h0x + w0[1] * h1x + w0[2] * h2x + w0[3] * cx;
      float a1 = b1 + w1[0] * h0y + w1[1] * h1y + w1[2] * h2y + w1[3] * cy;
      bf16x2 o;
      o[0] = (__bf16)(a0 * fsigmoid(a0));
      o[1] = (__bf16)(a1 * fsigmoid(a1));
      *(bf16x2*)(xcs + s * XST + d0) = o;
      h0x = h1x; h1x = h2x; h2x = cx;
      h0y = h1y; h1y = h2y; h2y = cy;
    }
  }
  __syncthreads();

  // ---- P1: Bmat = xc @ xpW^T (wave w -> tokens w*16..+15) -> Bms ----
  {
    f32x4 bacc = {};
#pragma unroll
    for (int k0 = 0; k0 < DI; k0 += 32) {
      bf16x8 a = *(const bf16x8*)(xcs + (w * 16 + l15) * XST + k0 + quad * 8);
      bf16x8 b = *(const bf16x8*)(xpW + l15 * DI + k0 + quad * 8);
      bacc = __builtin_amdgcn_mfma_f32_16x16x32_bf16(a, b, bacc, 0, 0, 0);
    }
#pragma unroll
    for (int rg = 0; rg < 4; ++rg)
      Bms[(w * 16 + quad * 4 + rg) * BMST + l15] = bacc[rg];
  }
  __syncthreads();

  // ---- P2: dt-GEMM: dtlin = xc @ dtW^T, wave owns channels [w*128, +128) ----
  int dbase = w * 128;
  f32x4 acc[4][8] = {};
#pragma unroll
  for (int k0 = 0; k0 < DI; k0 += 32) {
    bf16x8 af[4], bfr[8];
#pragma unroll
    for (int mi = 0; mi < 4; ++mi)
      af[mi] = *(const bf16x8*)(xcs + (mi * 16 + l15) * XST + k0 + quad * 8);
#pragma unroll
    for (int ni = 0; ni < 8; ++ni)
      bfr[ni] = *(const bf16x8*)(dtW + (size_t)(dbase + ni * 16 + l15) * DI + k0 + quad * 8);
#pragma unroll
    for (int mi = 0; mi < 4; ++mi)
#pragma unroll
      for (int ni = 0; ni < 8; ++ni)
        acc[mi][ni] = __builtin_amdgcn_mfma_f32_16x16x32_bf16(af[mi], bfr[ni], acc[mi][ni], 0, 0, 0);
  }

  // ---- P2b: ssm in-register: acc (dtlin) -> y ----
#pragma unroll
  for (int ni = 0; ni < 8; ++ni) {
    int d = dbase + ni * 16 + l15;
    float dtbv = dtb[d];
    float dpv = Dp[d];
    const f32x4* ar = (const f32x4*)(A2 + d * DSTATE);
    f32x4 av[4];
#pragma unroll
    for (int q = 0; q < 4; ++q) av[q] = ar[q];
#pragma unroll
    for (int mi = 0; mi < 4; ++mi) {
#pragma unroll
      for (int rg = 0; rg < 4; ++rg) {
        int tl = mi * 16 + quad * 4 + rg;
        const f32x4* br = (const f32x4*)(Bms + tl * BMST);
        float dt = fsoftplus(acc[mi][ni][rg] + dtbv);
        float s = 0.f;
#pragma unroll
        for (int q = 0; q < 4; ++q) {
          f32x4 bq = br[q];
#pragma unroll
          for (int j = 0; j < 4; ++j) s += fexp2(av[q][j] * dt) * bq[j];
        }
        float xcv = (float)xcs[tl * XST + d];
        acc[mi][ni][rg] = dt * xcv * s + dpv * xcv;
      }
    }
  }
  __syncthreads();  // all xcs reads done block-wide

  // ---- P3: write y (bf16) into xcs (overwrite) ----
#pragma unroll
  for (int mi = 0; mi < 4; ++mi)
#pragma unroll
    for (int ni = 0; ni < 8; ++ni)
#pragma unroll
      for (int rg = 0; rg < 4; ++rg) {
        int tl = mi * 16 + quad * 4 + rg;
        xcs[tl * XST + dbase + ni * 16 + l15] = (__bf16)acc[mi][ni][rg];
      }
  __syncthreads();

  // ---- P4: y *= silu(z)  (coalesced z reads from global) ----
  {
    int d0 = tid * 2;
#pragma unroll 4
    for (int s = 0; s < TW; ++s) {
      bf16x2 yv = *(bf16x2*)(xcs + s * XST + d0);
      bf16x2 zv = *(const bf16x2*)(xz + (size_t)(t0 + s) * 1024 + DI + d0);
      float z0 = (float)zv[0], z1 = (float)zv[1];
      bf16x2 o;
      o[0] = (__bf16)((float)yv[0] * z0 * fsigmoid(z0));
      o[1] = (__bf16)((float)yv[1] * z1 * fsigmoid(z1));
      *(bf16x2*)(xcs + s * XST + d0) = o;
    }
  }
  __syncthreads();

  // ---- P5: out-GEMM: yout = y' @ oW^T, wave owns cols [w*64, +64) ----
  int wn = w * 64;
  f32x4 oacc[4][4] = {};
#pragma unroll
  for (int k0 = 0; k0 < DI; k0 += 32) {
    bf16x8 af[4], bfr[4];
#pragma unroll
    for (int mi = 0; mi < 4; ++mi)
      af[mi] = *(const bf16x8*)(xcs + (mi * 16 + l15) * XST + k0 + quad * 8);
#pragma unroll
    for (int ni = 0; ni < 4; ++ni)
      bfr[ni] = *(const bf16x8*)(oW + (size_t)(wn + ni * 16 + l15) * DI + k0 + quad * 8);
#pragma unroll
    for (int mi = 0; mi < 4; ++mi)
#pragma unroll
      for (int ni = 0; ni < 4; ++ni)
        oacc[mi][ni] = __builtin_amdgcn_mfma_f32_16x16x32_bf16(af[mi], bfr[ni], oacc[mi][ni], 0, 0, 0);
  }

  // ---- P6: v = yout + x; rmsnorm; write x (fp32) + xb (bf16) ----
#pragma unroll
  for (int mi = 0; mi < 4; ++mi) {
#pragma unroll
    for (int rg = 0; rg < 4; ++rg) {
      int tl = mi * 16 + quad * 4 + rg;
      float sq = 0.f;
#pragma unroll
      for (int ni = 0; ni < 4; ++ni) {
        int c = wn + ni * 16 + l15;
        float v = oacc[mi][ni][rg] + x[(size_t)(t0 + tl) * DM + c];
        oacc[mi][ni][rg] = v;
        sq += v * v;
      }
      sq += __shfl_xor(sq, 1);
      sq += __shfl_xor(sq, 2);
      sq += __shfl_xor(sq, 4);
      sq += __shfl_xor(sq, 8);
      if (l15 == 0) rmsp[tl * 4 + w] = sq;
    }
  }
  __syncthreads();
#pragma unroll
  for (int mi = 0; mi < 4; ++mi) {
#pragma unroll
    for (int rg = 0; rg < 4; ++rg) {
      int tl = mi * 16 + quad * 4 + rg;
      float tot = rmsp[tl * 4 + 0] + rmsp[tl * 4 + 1] + rmsp[tl * 4 + 2] + rmsp[tl * 4 + 3];
      float r = rsqrtf(tot * (1.f / DM) + RMS_EPS);
#pragma unroll
      for (int ni = 0; ni < 4; ++ni) {
        int c = wn + ni * 16 + l15;
        float o = oacc[mi][ni][rg] * r * nw[c];
        x[(size_t)(t0 + tl) * DM + c] = o;
        xb[(size_t)(t0 + tl) * DM + c] = __float2bfloat16(o);
      }
    }
  }
}

// ---------------------------------------------------------------------------
// head-GEMM + entropy fused: wave owns 16 full rows (256 cols) -> in-wave
// entropy reduce, no cross-wave pass. grid = TT/64, block 256.
// No max-subtraction: logits bounded (~|l|<5), H = ln S - U/S is shift-invariant.
// ---------------------------------------------------------------------------
#define HST 264
__global__ __launch_bounds__(256) void head_entropy(
    const __hip_bfloat16* __restrict__ xb, const __bf16* __restrict__ hW,
    float* __restrict__ ent) {
  __shared__ __align__(16) __bf16 as[64 * HST];
  int tid = threadIdx.x;
  int lane = tid & 63;
  int w = tid >> 6;
  int quad = lane >> 4;
  int l15 = lane & 15;
  int t0 = blockIdx.x * 64;
  // stage xb tile (64x256) with padded stride
  for (int i = tid; i < 64 * 32; i += 256) {
    int r = i >> 5, c8 = (i & 31) * 8;
    *(bf16x8*)(as + r * HST + c8) = *(const bf16x8*)(xb + (size_t)(t0 + r) * DM + c8);
  }
  __syncthreads();
  f32x4 acc[16] = {};
  int mrow = w * 16 + l15;
#pragma unroll
  for (int k0 = 0; k0 < DM; k0 += 32) {
    bf16x8 a = *(const bf16x8*)(as + mrow * HST + k0 + quad * 8);
#pragma unroll
    for (int ni = 0; ni < 16; ++ni) {
      bf16x8 b = *(const bf16x8*)(hW + (size_t)(ni * 16 + l15) * DM + k0 + quad * 8);
      acc[ni] = __builtin_amdgcn_mfma_f32_16x16x32_bf16(a, b, acc[ni], 0, 0, 0);
    }
  }
#pragma unroll
  for (int rg = 0; rg < 4; ++rg) {
    float s = 0.f, u = 0.f;
#pragma unroll
    for (int ni = 0; ni < 16; ++ni) {
      float l = acc[ni][rg];
      float e = fexp(l);
      s += e;
      u += e * l;
    }
    s += __shfl_xor(s, 1); u += __shfl_xor(u, 1);
    s += __shfl_xor(s, 2); u += __shfl_xor(u, 2);
    s += __shfl_xor(s, 4); u += __shfl_xor(u, 4);
    s += __shfl_xor(s, 8); u += __shfl_xor(u, 8);
    if (l15 == 0) {
      int t = t0 + w * 16 + quad * 4 + rg;
      ent[t] = (flog(s) - u * frcp(s)) * (1.f / LOG_VOCAB);
    }
  }
}

// boundary scan + byte_to_patch + patch starts. 1 block, 8 waves (1 per batch).
__global__ void scan_kernel(const float* __restrict__ ent, float* __restrict__ btp_out,
                            int* __restrict__ pstart, int* __restrict__ npatch) {
  __shared__ unsigned long long masks[BB][32];
  __shared__ int wpre[BB][33];
  int tid = threadIdx.x;
  int w = tid >> 6, lane = tid & 63;
  int b = w;
  int size = 1;
  for (int w64 = 0; w64 < 32; ++w64) {
    int s = w64 * 64 + lane;
    float e = ent[b * SS + s];
    unsigned long long cb = __ballot(e > 0.5f);
    if (lane == 0) {
      unsigned long long bits;
      if (w64 == 0) {
        bits = 1ull;
        for (int j = 1; j < 64; ++j) {
          int c = (int)((cb >> j) & 1ull);
          int nb = c | (size >= 8);
          size = nb ? 1 : size + 1;
          bits |= ((unsigned long long)nb) << j;
        }
      } else if (cb == ~0ull) {
        bits = cb;
        size = 1;
      } else {
        bits = 0ull;
        for (int j = 0; j < 64; ++j) {
          int c = (int)((cb >> j) & 1ull);
          int nb = c | (size >= 8);
          size = nb ? 1 : size + 1;
          bits |= ((unsigned long long)nb) << j;
        }
      }
      masks[w][w64] = bits;
    }
  }
  __syncthreads();
  if (lane == 0) {
    int acc = 0;
    for (int i = 0; i < 32; ++i) {
      wpre[w][i] = acc;
      acc += __popcll(masks[w][i]);
    }
    wpre[w][32] = acc;
    npatch[b] = acc;
  }
  __syncthreads();
  for (int w64 = 0; w64 < 32; ++w64) {
    int s = w64 * 64 + lane;
    unsigned long long word = masks[w][w64];
    unsigned long long below =
        word & ((lane == 63) ? ~0ull : ((1ull << (lane + 1)) - 1ull));
    int btp = wpre[w][w64] + __popcll(below) - 1;
    btp_out[b * SS + s] = (float)btp;
    if ((word >> lane) & 1ull) pstart[b * SS + btp] = s;
  }
}

// per-patch mean pooling (contiguous ranges), zero-fill padding patches
__global__ void patch_kernel(const float* __restrict__ bemb, const int* __restrict__ pstart,
                             const int* __restrict__ npatch, float* __restrict__ pe_out,
                             float* __restrict__ plen_out) {
  int bp = blockIdx.x;
  int b = bp >> 11;
  int p = bp & (SS - 1);
  int c = threadIdx.x;
  int np = npatch[b];
  size_t outidx = (size_t)bp * DM + c;
  if (p >= np) {
    pe_out[outidx] = 0.f;
    if (c == 0) plen_out[bp] = 0.f;
    return;
  }
  int start = pstart[b * SS + p];
  int end = (p + 1 < np) ? pstart[b * SS + p + 1] : SS;
  float acc = 0.f;
  for (int t = start; t < end; ++t) acc += bemb[((size_t)b * SS + t) * DM + c];
  pe_out[outidx] = acc * frcp((float)(end - start));
  if (c == 0) plen_out[bp] = (float)(end - start);
}

// ---------------------------------------------------------------------------
// Launcher — 7 dispatches total
// ---------------------------------------------------------------------------
extern "C" void kernel_launch(void* const* d_in, const int* in_sizes, int n_in,
                              void* d_out, int out_size, void* d_ws, size_t ws_size,
                              hipStream_t stream) {
  const int* bytes = (const int*)d_in[0];
  const float* bemb = (const float*)d_in[1];
  const float* embed_w = (const float*)d_in[2];
  const float* in_proj_w = (const float*)d_in[3];
  const float* conv_w = (const float*)d_in[4];
  const float* conv_b = (const float*)d_in[5];
  const float* x_proj_w = (const float*)d_in[6];
  const float* dt_w = (const float*)d_in[7];
  const float* dt_b = (const float*)d_in[8];
  const float* A_log = (const float*)d_in[9];
  const float* D_param = (const float*)d_in[10];
  const float* out_w = (const float*)d_in[11];
  const float* norm_w = (const float*)d_in[12];
  const float* head_w = (const float*)d_in[13];

  float* out = (float*)d_out;
  float* pe_out = out;                      // (B,S,DM)
  float* plen_out = out + (size_t)TT * DM;  // (B,S)
  float* btp_out = plen_out + TT;           // (B,S)

  char* wsb = (char*)d_ws;
  size_t off = 0;
  auto alloc = [&](size_t bytes_) -> void* {
    void* p = wsb + off;
    off += (bytes_ + 255) & ~(size_t)255;
    return p;
  };
  float* A2 = (float*)alloc((size_t)NLAYERS * DI * DSTATE * 4);
  float* x = (float*)alloc((size_t)TT * DM * 4);
  __hip_bfloat16* xb = (__hip_bfloat16*)alloc((size_t)TT * DM * 2);
  __hip_bfloat16* xz = (__hip_bfloat16*)alloc((size_t)TT * 2 * DI * 2);
  float* ent = (float*)alloc((size_t)TT * 4);
  int* pstart = (int*)alloc((size_t)TT * 4);
  int* npatch = (int*)alloc(256);
  __hip_bfloat16* inWt = (__hip_bfloat16*)alloc((size_t)NLAYERS * 2 * DI * DM * 2);
  __hip_bfloat16* dtWt = (__hip_bfloat16*)alloc((size_t)NLAYERS * DI * DI * 2);
  __hip_bfloat16* oWt = (__hip_bfloat16*)alloc((size_t)NLAYERS * DM * DI * 2);
  __hip_bfloat16* xpWt = (__hip_bfloat16*)alloc((size_t)NLAYERS * 32 * DI * 2);
  __hip_bfloat16* headWt = (__hip_bfloat16*)alloc((size_t)VOCAB * DM * 2);

  // 1: weight prep + embedding
  prep_kernel<<<(PREP_ALL + 255) / 256, 256, 0, stream>>>(
      A_log, A2, head_w, headWt, in_proj_w, inWt, dt_w, dtWt, out_w, oWt,
      x_proj_w, xpWt, bytes, embed_w, x, xb);

  // 2..5: two Mamba layers, 2 dispatches each
  size_t fused_lds = (size_t)TW * XST * 2 + (size_t)TW * BMST * 4 + (size_t)TW * 4 * 4;
  for (int l = 0; l < NLAYERS; ++l) {
    gemm_mfma<<<dim3(2 * DI / 128, TT / 128), 256, 0, stream>>>(
        (const __bf16*)xb, (const __bf16*)(inWt + (size_t)l * 2 * DI * DM),
        (__hip_bfloat16*)xz, TT, 2 * DI, DM);
    mamba_fused<<<TT / TW, 256, fused_lds, stream>>>(
        xz, (const __bf16*)(dtWt + (size_t)l * DI * DI),
        (const __bf16*)(oWt + (size_t)l * DM * DI),
        (const __bf16*)(xpWt + (size_t)l * 32 * DI),
        conv_w + (size_t)l * DI * DCONV, conv_b + (size_t)l * DI,
        A2 + (size_t)l * DI * DSTATE, dt_b + (size_t)l * DI,
        D_param + (size_t)l * DI, norm_w + (size_t)l * DM, x, xb);
  }

  // 6: head + entropy
  head_entropy<<<TT / 64, 256, 0, stream>>>(xb, (const __bf16*)headWt, ent);

  // 7: boundary scan
  scan_kernel<<<1, 512, 0, stream>>>(ent, btp_out, pstart, npatch);

  // 8: patch mean pooling
  patch_kernel<<<TT, DM, 0, stream>>>(bemb, pstart, npatch, pe_out, plen_out);
}